// Round 2
// baseline (799.410 us; speedup 1.0000x reference)
//
#include <hip/hip_runtime.h>

#define T_LEN 1024
#define M_DIM 128
#define B_NUM 64

// One block (2 waves, 128 threads) per batch. Lane j holds W column j
// (w[i] = exp(A_trans[i][j])) in 128 VGPRs. Exp-space recurrence:
//   u_t[j] = (sum_i u_{t-1}[i] * w[i][j]) * exp(P_t[j])   (one barrier/step,
// double-buffered u in LDS). Renormalize every 4 steps with a lagged max
// (snapshot at t%4==0, applied folded into exp-factor at t%4==1).
// The label-path score sY has no sequential dependency -> gathered up front.
__global__ __launch_bounds__(128, 1) void crf_fwd(
    const float* __restrict__ P, const float* __restrict__ A,
    const int* __restrict__ Y, const int* __restrict__ L,
    float* __restrict__ out)
{
  const int b    = blockIdx.x;
  const int tid  = threadIdx.x;   // j = tid, 0..127
  const int lane = tid & 63;
  const int wid  = tid >> 6;

  __shared__ __align__(16) float u_lds[2][M_DIM];
  __shared__ float red[4];    // [0,1]: wave max snapshot; [2,3]: final sums
  __shared__ float sY_sh[2];

  const int Lb = L[b];
  const float* Pb = P + (size_t)b * T_LEN * M_DIM;
  const int*   Yb = Y + b * T_LEN;

  // W column j in registers (coalesced: lanes are consecutive j).
  float w[M_DIM];
  #pragma unroll
  for (int i = 0; i < M_DIM; ++i)
    w[i] = __expf(A[i * M_DIM + tid]);

  // ---- sY path score: no sequential dependency, gather in parallel ----
  float mySY = 0.f;
  for (int tt = tid; tt < Lb; tt += 128) {
    int yt = Yb[tt];
    float term = Pb[tt * M_DIM + yt];
    term += (tt == 0) ? A[M_DIM * M_DIM + yt]          // A_start[y0]
                      : A[Yb[tt - 1] * M_DIM + yt];    // A_trans[y_{t-1}][y_t]
    mySY += term;
  }
  #pragma unroll
  for (int d = 1; d < 64; d <<= 1) mySY += __shfl_xor(mySY, d);
  if (lane == 0) sY_sh[wid] = mySY;

  // ---- t = 0 ----
  float p_cur = Pb[tid];
  float un = __expf(p_cur + A[M_DIM * M_DIM + tid]);   // u0 = exp(S0), C0 = 0
  u_lds[0][tid] = un;
  {
    float zm = un;   // snapshot at t=0 (applied at t=1)
    #pragma unroll
    for (int d = 1; d < 64; d <<= 1) zm = fmaxf(zm, __shfl_xor(zm, d));
    if (lane == 0) red[wid] = zm;
  }
  float C = 0.f;
  p_cur = Pb[M_DIM + tid];   // prefetch row t=1 (valid memory even if Lb==1)
  __syncthreads();

  if (Lb == 1) {
    float zs = un;
    #pragma unroll
    for (int d = 1; d < 64; d <<= 1) zs += __shfl_xor(zs, d);
    if (lane == 0) red[2 + wid] = zs;
    __syncthreads();
    if (tid == 0) out[b] = __logf(red[2] + red[3]) - (sY_sh[0] + sY_sh[1]);
    return;
  }

  int cur = 0;
  for (int t = 1;; ++t) {
    // exp factor + pending renorm scale: off the u-dependent chain
    float ep = __expf(p_cur);
    if ((t & 3) == 1) {
      float Z = fmaxf(red[0], red[1]);
      C += __logf(Z);
      ep *= __builtin_amdgcn_rcpf(Z);
    }

    // ---- matvec: v[j] = sum_i u[i] * w[i] (32 broadcast b128 reads) ----
    const float4* u4 = (const float4*)(u_lds[cur]);
    float a0 = 0.f, a1 = 0.f, a2 = 0.f, a3 = 0.f;
    #pragma unroll
    for (int k = 0; k < 32; ++k) {
      float4 uu = u4[k];
      a0 = fmaf(uu.x, w[4 * k + 0], a0);
      a1 = fmaf(uu.y, w[4 * k + 1], a1);
      a2 = fmaf(uu.z, w[4 * k + 2], a2);
      a3 = fmaf(uu.w, w[4 * k + 3], a3);
    }
    un = ((a0 + a1) + (a2 + a3)) * ep;
    u_lds[cur ^ 1][tid] = un;

    // prefetch next P row (clamped; off critical path)
    int tn = (t + 1 < T_LEN) ? t + 1 : T_LEN - 1;
    float p_next = Pb[tn * M_DIM + tid];

    const bool last = (t == Lb - 1);
    if (last) {
      float zs = un;
      #pragma unroll
      for (int d = 1; d < 64; d <<= 1) zs += __shfl_xor(zs, d);
      if (lane == 0) red[2 + wid] = zs;
    } else if ((t & 3) == 0) {
      float zm = un;   // snapshot, applied at t+1
      #pragma unroll
      for (int d = 1; d < 64; d <<= 1) zm = fmaxf(zm, __shfl_xor(zm, d));
      if (lane == 0) red[wid] = zm;
    }
    __syncthreads();

    if (last) {
      if (tid == 0) out[b] = __logf(red[2] + red[3]) + C - (sY_sh[0] + sY_sh[1]);
      return;
    }
    p_cur = p_next;
    cur ^= 1;
  }
}

extern "C" void kernel_launch(void* const* d_in, const int* in_sizes, int n_in,
                              void* d_out, int out_size, void* d_ws, size_t ws_size,
                              hipStream_t stream) {
  const float* P = (const float*)d_in[0];
  const float* A = (const float*)d_in[1];
  const int*   Y = (const int*)d_in[2];
  const int*   L = (const int*)d_in[3];
  float* o = (float*)d_out;
  hipLaunchKernelGGL(crf_fwd, dim3(B_NUM), dim3(128), 0, stream, P, A, Y, L, o);
}

// Round 3
// 476.743 us; speedup vs baseline: 1.6768x; 1.6768x over previous
//
#include <hip/hip_runtime.h>

#define T_LEN 1024
#define M_DIM 128
#define B_NUM 64

// One block (512 thr, 8 waves) per batch. Thread = (j = tid>>2, c = tid&3):
// lane (c,j) holds w[i][j] = exp(A_trans[i][j]) for the 32 i's of chunk c in
// 32 VGPRs. Exp-space recurrence u_t = (W^T u_{t-1}) .* exp(P_t), one barrier
// per step (double-buffered u). The 4 chunk-partials for j sit in one lane
// quad -> reduced by 2 DPP shuffles (no LDS round-trip). Renormalize every
// 4 steps via lagged wave-max snapshot. Path score sY hoisted (no seq dep).
__global__ __launch_bounds__(512, 1) void crf_fwd(
    const float* __restrict__ P, const float* __restrict__ A,
    const int* __restrict__ Y, const int* __restrict__ L,
    float* __restrict__ out)
{
  const int b    = blockIdx.x;
  const int tid  = threadIdx.x;
  const int lane = tid & 63;
  const int wid  = tid >> 6;
  const int j    = tid >> 2;    // output state 0..127
  const int c    = tid & 3;     // i-chunk 0..3

  __shared__ __align__(16) float u_lds[2][M_DIM];
  __shared__ __align__(16) float red[8];   // per-wave max snapshots
  __shared__ float red_sum[8];
  __shared__ float sY_sh[8];

  const int Lb = L[b];
  const float* Pb = P + (size_t)b * T_LEN * M_DIM;
  const int*   Yb = Y + b * T_LEN;

  // W chunk in regs, stored in ds-read-slot order with per-c rotation
  // (start slot 2c) so the 4 c-groups' broadcast reads hit disjoint banks.
  float w[32];
  const int r0 = (2 * c) & 7;
  #pragma unroll
  for (int k = 0; k < 8; ++k) {
    int slot  = (r0 + k) & 7;
    int ibase = c * 32 + slot * 4;
    #pragma unroll
    for (int e = 0; e < 4; ++e)
      w[k * 4 + e] = __expf(A[(ibase + e) * M_DIM + j]);
  }

  // ---- path score sY: no sequential dependency, gather in parallel ----
  float mySY = 0.f;
  for (int tt = tid; tt < Lb; tt += 512) {
    int yt = Yb[tt];
    float term = Pb[tt * M_DIM + yt];
    term += (tt == 0) ? A[M_DIM * M_DIM + yt] : A[Yb[tt - 1] * M_DIM + yt];
    mySY += term;
  }
  #pragma unroll
  for (int d = 1; d < 64; d <<= 1) mySY += __shfl_xor(mySY, d);
  if (lane == 0) sY_sh[wid] = mySY;

  // ---- t = 0 ----
  float un = __expf(Pb[j] + A[M_DIM * M_DIM + j]);   // u0, C0 = 0
  if (c == 0) u_lds[0][j] = un;
  {
    float zm = un;   // snapshot (applied at t=1); un uniform in quad -> d>=4
    #pragma unroll
    for (int d = 4; d < 64; d <<= 1) zm = fmaxf(zm, __shfl_xor(zm, d));
    if (lane == 0) red[wid] = zm;
  }
  float p_cur = Pb[M_DIM + j];   // prefetch row t=1 (always a valid row)
  if (Lb == 1) {
    float zs = un;               // wave sum = 4 * sum over its 16 j's
    #pragma unroll
    for (int d = 1; d < 64; d <<= 1) zs += __shfl_xor(zs, d);
    if (lane == 0) red_sum[wid] = zs;
  }
  __syncthreads();

  if (Lb == 1) {
    if (tid == 0) {
      float s = 0.f, sy = 0.f;
      #pragma unroll
      for (int q = 0; q < 8; ++q) { s += red_sum[q]; sy += sY_sh[q]; }
      out[b] = __logf(s * 0.25f) - sy;
    }
    return;
  }

  float C = 0.f;
  int cur = 0;
  for (int t = 1;; ++t) {
    // exp factor (+ pending renorm) — independent of the u chain
    float ep = __expf(p_cur);
    if ((t & 3) == 1) {
      float4 ra = *(const float4*)&red[0];
      float4 rb = *(const float4*)&red[4];
      float Z = fmaxf(fmaxf(fmaxf(ra.x, ra.y), fmaxf(ra.z, ra.w)),
                      fmaxf(fmaxf(rb.x, rb.y), fmaxf(rb.z, rb.w)));
      C += __logf(Z);
      ep *= __builtin_amdgcn_rcpf(Z);
    }

    // ---- matvec: 8 broadcast ds_read_b128 (disjoint banks across c) ----
    const float4* u4 = (const float4*)(u_lds[cur]);
    float a0 = 0.f, a1 = 0.f, a2 = 0.f, a3 = 0.f;
    #pragma unroll
    for (int k = 0; k < 8; ++k) {
      float4 uu = u4[c * 8 + ((r0 + k) & 7)];
      a0 = fmaf(uu.x, w[4 * k + 0], a0);
      a1 = fmaf(uu.y, w[4 * k + 1], a1);
      a2 = fmaf(uu.z, w[4 * k + 2], a2);
      a3 = fmaf(uu.w, w[4 * k + 3], a3);
    }
    float v = (a0 + a1) + (a2 + a3);
    v += __shfl_xor(v, 1);   // quad reduce across c (DPP)
    v += __shfl_xor(v, 2);
    un = v * ep;
    if (c == 0) u_lds[cur ^ 1][j] = un;

    int tn = (t + 1 < T_LEN) ? t + 1 : T_LEN - 1;
    float p_next = Pb[tn * M_DIM + j];   // prefetch, off chain

    const bool last = (t == Lb - 1);
    if (last) {
      float zs = un;
      #pragma unroll
      for (int d = 1; d < 64; d <<= 1) zs += __shfl_xor(zs, d);
      if (lane == 0) red_sum[wid] = zs;
    } else if ((t & 3) == 0) {
      float zm = un;   // snapshot, applied at t+1
      #pragma unroll
      for (int d = 4; d < 64; d <<= 1) zm = fmaxf(zm, __shfl_xor(zm, d));
      if (lane == 0) red[wid] = zm;
    }
    __syncthreads();

    if (last) {
      if (tid == 0) {
        float s = 0.f, sy = 0.f;
        #pragma unroll
        for (int q = 0; q < 8; ++q) { s += red_sum[q]; sy += sY_sh[q]; }
        out[b] = __logf(s * 0.25f) + C - sy;
      }
      return;
    }
    p_cur = p_next;
    cur ^= 1;
  }
}

extern "C" void kernel_launch(void* const* d_in, const int* in_sizes, int n_in,
                              void* d_out, int out_size, void* d_ws, size_t ws_size,
                              hipStream_t stream) {
  const float* P = (const float*)d_in[0];
  const float* A = (const float*)d_in[1];
  const int*   Y = (const int*)d_in[2];
  const int*   L = (const int*)d_in[3];
  float* o = (float*)d_out;
  hipLaunchKernelGGL(crf_fwd, dim3(B_NUM), dim3(512), 0, stream, P, A, Y, L, o);
}

// Round 4
// 414.310 us; speedup vs baseline: 1.9295x; 1.1507x over previous
//
#include <hip/hip_runtime.h>

#define T_LEN 1024
#define M_DIM 128
#define B_NUM 64

// One block (512 thr, 8 waves) per batch. Thread = (j = tid>>2, c = tid&3):
// lane (c,j) holds w[i][j] = exp(A_trans[i][j]) for chunk c's 32 i's in VGPRs.
// Exp-space recurrence u_t = (W^T u_{t-1}) .* exp(P_t); one barrier/step
// (double-buffered u); quad-partials reduced by 2 DPP shuffles. Renorm every
// 4 steps (SNAP at t%4==0, APPLY at t%4==1). sY path score hoisted.
// Time loop unrolled x8 with an 8-row P prefetch burst into static regs so
// only 1-in-8 barriers drains a pending global load (vmcnt(0) before
// s_barrier is mandatory; a per-step fresh load stalled every barrier).
__global__ __launch_bounds__(512, 1) void crf_fwd(
    const float* __restrict__ P, const float* __restrict__ A,
    const int* __restrict__ Y, const int* __restrict__ L,
    float* __restrict__ out)
{
  const int b    = blockIdx.x;
  const int tid  = threadIdx.x;
  const int lane = tid & 63;
  const int wid  = tid >> 6;
  const int j    = tid >> 2;    // output state 0..127
  const int c    = tid & 3;     // i-chunk 0..3

  __shared__ __align__(16) float u_lds[2][M_DIM];
  __shared__ __align__(16) float red[8];   // per-wave max snapshots
  __shared__ float red_sum[8];
  __shared__ float sY_sh[8];

  const int Lb = L[b];
  const float* Pb = P + (size_t)b * T_LEN * M_DIM;
  const int*   Yb = Y + b * T_LEN;

  // W chunk in regs, slot order rotated per c so broadcast reads are
  // bank-disjoint across the 4 c-groups.
  float w[32];
  const int r0 = (2 * c) & 7;
  #pragma unroll
  for (int k = 0; k < 8; ++k) {
    int slot  = (r0 + k) & 7;
    int ibase = c * 32 + slot * 4;
    #pragma unroll
    for (int e = 0; e < 4; ++e)
      w[k * 4 + e] = __expf(A[(ibase + e) * M_DIM + j]);
  }

  // ---- path score sY: no sequential dependency, gather in parallel ----
  float mySY = 0.f;
  for (int tt = tid; tt < Lb; tt += 512) {
    int yt = Yb[tt];
    float term = Pb[tt * M_DIM + yt];
    term += (tt == 0) ? A[M_DIM * M_DIM + yt] : A[Yb[tt - 1] * M_DIM + yt];
    mySY += term;
  }
  #pragma unroll
  for (int d = 1; d < 64; d <<= 1) mySY += __shfl_xor(mySY, d);
  if (lane == 0) sY_sh[wid] = mySY;

  // ---- t = 0 ----
  float un = __expf(Pb[j] + A[M_DIM * M_DIM + j]);   // u0, C0 = 0
  if (c == 0) u_lds[0][j] = un;
  {
    float zm = un;   // snapshot (applied at t=1); un uniform in quad -> d>=4
    #pragma unroll
    for (int d = 4; d < 64; d <<= 1) zm = fmaxf(zm, __shfl_xor(zm, d));
    if (lane == 0) red[wid] = zm;
  }
  float C = 0.f;
  float p_cur = Pb[M_DIM + j];   // row t=1 (always a valid row)
  if (Lb == 1) {
    float zs = un;
    #pragma unroll
    for (int d = 1; d < 64; d <<= 1) zs += __shfl_xor(zs, d);
    if (lane == 0) red_sum[wid] = zs;
  }
  __syncthreads();
  if (Lb == 1) goto finish;

// Sub-step macro. MODE: 0 = plain, 1 = APPLY renorm (t%4==1), 2 = SNAP (t%4==0).
#define CRF_STEP(S, MODE, PNEXT)                                          \
  {                                                                       \
    float ep = __expf(p_cur);                                             \
    if ((MODE) == 1) {                                                    \
      float4 ra = *(const float4*)&red[0];                                \
      float4 rb = *(const float4*)&red[4];                                \
      float Z = fmaxf(fmaxf(fmaxf(ra.x, ra.y), fmaxf(ra.z, ra.w)),        \
                      fmaxf(fmaxf(rb.x, rb.y), fmaxf(rb.z, rb.w)));       \
      C += __logf(Z);                                                     \
      ep *= __builtin_amdgcn_rcpf(Z);                                     \
    }                                                                     \
    const float4* u4 = (const float4*)(u_lds[cur]);                       \
    float a0 = 0.f, a1 = 0.f, a2 = 0.f, a3 = 0.f;                         \
    _Pragma("unroll")                                                     \
    for (int k = 0; k < 8; ++k) {                                         \
      float4 uu = u4[c * 8 + ((r0 + k) & 7)];                             \
      a0 = fmaf(uu.x, w[4 * k + 0], a0);                                  \
      a1 = fmaf(uu.y, w[4 * k + 1], a1);                                  \
      a2 = fmaf(uu.z, w[4 * k + 2], a2);                                  \
      a3 = fmaf(uu.w, w[4 * k + 3], a3);                                  \
    }                                                                     \
    float v = (a0 + a1) + (a2 + a3);                                      \
    v += __shfl_xor(v, 1);                                                \
    v += __shfl_xor(v, 2);                                                \
    un = v * ep;                                                          \
    if (c == 0) u_lds[cur ^ 1][j] = un;                                   \
    const bool last = (tb + (S) == Lb - 1);                               \
    if (last) {                                                           \
      float zs = un;                                                      \
      _Pragma("unroll")                                                   \
      for (int d = 1; d < 64; d <<= 1) zs += __shfl_xor(zs, d);           \
      if (lane == 0) red_sum[wid] = zs;                                   \
    } else if ((MODE) == 2) {                                             \
      float zm = un;                                                      \
      _Pragma("unroll")                                                   \
      for (int d = 4; d < 64; d <<= 1) zm = fmaxf(zm, __shfl_xor(zm, d)); \
      if (lane == 0) red[wid] = zm;                                       \
    }                                                                     \
    __syncthreads();                                                      \
    if (last) goto finish;                                                \
    p_cur = (PNEXT);                                                      \
    cur ^= 1;                                                             \
  }

  {
    int cur = 0;
    int tb  = 1;   // iteration handles steps tb..tb+7; tb ≡ 1 (mod 8)
    for (;;) {
      // Burst-prefetch P rows tb+1..tb+8 (clamped) into static regs.
      float pn0, pn1, pn2, pn3, pn4, pn5, pn6, pn7;
      {
        int r;
        r = tb + 1; r = r < T_LEN ? r : T_LEN - 1; pn0 = Pb[r * M_DIM + j];
        r = tb + 2; r = r < T_LEN ? r : T_LEN - 1; pn1 = Pb[r * M_DIM + j];
        r = tb + 3; r = r < T_LEN ? r : T_LEN - 1; pn2 = Pb[r * M_DIM + j];
        r = tb + 4; r = r < T_LEN ? r : T_LEN - 1; pn3 = Pb[r * M_DIM + j];
        r = tb + 5; r = r < T_LEN ? r : T_LEN - 1; pn4 = Pb[r * M_DIM + j];
        r = tb + 6; r = r < T_LEN ? r : T_LEN - 1; pn5 = Pb[r * M_DIM + j];
        r = tb + 7; r = r < T_LEN ? r : T_LEN - 1; pn6 = Pb[r * M_DIM + j];
        r = tb + 8; r = r < T_LEN ? r : T_LEN - 1; pn7 = Pb[r * M_DIM + j];
      }
      // t mod 4 over sub-steps: 1,2,3,0,1,2,3,0
      CRF_STEP(0, 1, pn0)
      CRF_STEP(1, 0, pn1)
      CRF_STEP(2, 0, pn2)
      CRF_STEP(3, 2, pn3)
      CRF_STEP(4, 1, pn4)
      CRF_STEP(5, 0, pn5)
      CRF_STEP(6, 0, pn6)
      CRF_STEP(7, 2, pn7)
      tb += 8;
    }
  }

finish:
  if (tid == 0) {
    float s = 0.f, sy = 0.f;
    #pragma unroll
    for (int q = 0; q < 8; ++q) { s += red_sum[q]; sy += sY_sh[q]; }
    out[b] = __logf(s * 0.25f) + C - sy;
  }
}

extern "C" void kernel_launch(void* const* d_in, const int* in_sizes, int n_in,
                              void* d_out, int out_size, void* d_ws, size_t ws_size,
                              hipStream_t stream) {
  const float* P = (const float*)d_in[0];
  const float* A = (const float*)d_in[1];
  const int*   Y = (const int*)d_in[2];
  const int*   L = (const int*)d_in[3];
  float* o = (float*)d_out;
  hipLaunchKernelGGL(crf_fwd, dim3(B_NUM), dim3(512), 0, stream, P, A, Y, L, o);
}